// Round 1
// baseline (2460.016 us; speedup 1.0000x reference)
//
#include <hip/hip_runtime.h>
#include <stdint.h>

// GRUClassifier: 2-layer bidirectional GRU (H=128, T=512, B=512) + FC head.
// Decomposition: batch-partitioned persistent scan workgroups, weights as
// register-resident bf16 MFMA fragments, fp32 state/gates.

#define Hh   128
#define Tt   512
#define Bb   512
#define BC   16      // batch rows per workgroup
#define THREADS 512  // 8 waves

using s16x8 = __attribute__((ext_vector_type(8))) short;  // 8 bf16
using f32x4 = __attribute__((ext_vector_type(4))) float;

__device__ __forceinline__ unsigned short f2bf(float f) {
    union { float f; unsigned int u; } v; v.f = f;
    unsigned int u = v.u;
    u += 0x7fffu + ((u >> 16) & 1u);   // RNE
    return (unsigned short)(u >> 16);
}

__device__ __forceinline__ float sigmoidf_(float x) { return 1.0f / (1.0f + __expf(-x)); }
__device__ __forceinline__ float tanhf_(float x)    { return 1.0f - 2.0f / (1.0f + __expf(2.0f * x)); }

// ---------------------------------------------------------------------------
// Layer 0 scan: input dim 4 (x-projection via scalar FMA), Gh via MFMA K=128.
// grid = 64 (dir*32 + chunk), block = 512.
// ---------------------------------------------------------------------------
__global__ __launch_bounds__(THREADS, 2) void gru_l0(
    const float* __restrict__ x,
    const float* __restrict__ wih_f, const float* __restrict__ whh_f,
    const float* __restrict__ bih_f, const float* __restrict__ bhh_f,
    const float* __restrict__ wih_b, const float* __restrict__ whh_b,
    const float* __restrict__ bih_b, const float* __restrict__ bhh_b,
    unsigned short* __restrict__ y0)
{
    const int tid  = threadIdx.x;
    const int wave = tid >> 6;
    const int lane = tid & 63;
    const int lcol = lane & 15;
    const int quad = lane >> 4;
    const int dir   = blockIdx.x >> 5;
    const int chunk = blockIdx.x & 31;
    const int b0 = chunk * BC;

    const float* wih = dir ? wih_b : wih_f;
    const float* whh = dir ? whh_b : whh_f;
    const float* bih = dir ? bih_b : bih_f;
    const float* bhh = dir ? bhh_b : bhh_f;

    __shared__ __align__(16) unsigned short lds_ah[BC][136]; // h bf16, padded
    __shared__ __align__(16) float lds_gh[BC][396];          // Gh fp32, padded
    __shared__ __align__(16) float lds_x[BC][4];

    // --- preload w_hh B-fragments: wave owns n-tiles 3*wave+p (p=0..2)
    // lane holds W[n_base+lcol][kk*32 + quad*8 + j], j=0..7
    s16x8 bh[3][4];
    float bias_h[3];
#pragma unroll
    for (int p = 0; p < 3; ++p) {
        const int nrow = (3 * wave + p) * 16 + lcol;
        bias_h[p] = bhh[nrow];
#pragma unroll
        for (int kk = 0; kk < 4; ++kk) {
            const float* src = &whh[nrow * Hh + kk * 32 + quad * 8];
            s16x8 f;
#pragma unroll
            for (int j = 0; j < 8; ++j) f[j] = (short)f2bf(src[j]);
            bh[p][kk] = f;
        }
    }

    // --- gate-thread setup: thread owns batch row gb, cols j0..j0+3
    const int gb = tid >> 5;
    const int j0 = (tid & 31) * 4;
    float wir[3][4][4];   // [gate d][i][feature f] input weights (din=4)
    float bi3[3][4];
#pragma unroll
    for (int d = 0; d < 3; ++d)
#pragma unroll
        for (int i = 0; i < 4; ++i) {
            const int col = j0 + i + 128 * d;
            bi3[d][i] = bih[col];
#pragma unroll
            for (int f = 0; f < 4; ++f) wir[d][i][f] = wih[col * 4 + f];
        }

    float hreg[4] = {0.f, 0.f, 0.f, 0.f};

    for (int idx = tid; idx < BC * 136; idx += THREADS)
        ((unsigned short*)lds_ah)[idx] = 0;
    __syncthreads();

    for (int s = 0; s < Tt; ++s) {
        const int t = dir ? (Tt - 1 - s) : s;

        if (tid < BC) { // x is [B, T, 4]
            const float4 xv = *(const float4*)&x[((size_t)(b0 + tid) * Tt + t) * 4];
            *(float4*)&lds_x[tid][0] = xv;
        }

        // Gh = h @ whh^T + bhh
        f32x4 acc[3];
#pragma unroll
        for (int p = 0; p < 3; ++p) acc[p] = {bias_h[p], bias_h[p], bias_h[p], bias_h[p]};
#pragma unroll
        for (int kk = 0; kk < 4; ++kk) {
            const s16x8 a = *(const s16x8*)&lds_ah[lcol][kk * 32 + quad * 8];
#pragma unroll
            for (int p = 0; p < 3; ++p)
                acc[p] = __builtin_amdgcn_mfma_f32_16x16x32_bf16(a, bh[p][kk], acc[p], 0, 0, 0);
        }
#pragma unroll
        for (int p = 0; p < 3; ++p) {
            const int ncol = (3 * wave + p) * 16 + lcol;
#pragma unroll
            for (int i = 0; i < 4; ++i)
                lds_gh[quad * 4 + i][ncol] = acc[p][i];  // C/D: row=quad*4+i, col=lcol
        }
        __syncthreads();

        // gates
        float xs[4];  *(float4*)xs  = *(const float4*)&lds_x[gb][0];
        float ghr[4]; *(float4*)ghr = *(const float4*)&lds_gh[gb][j0];
        float ghz[4]; *(float4*)ghz = *(const float4*)&lds_gh[gb][j0 + 128];
        float ghn[4]; *(float4*)ghn = *(const float4*)&lds_gh[gb][j0 + 256];
#pragma unroll
        for (int i = 0; i < 4; ++i) {
            float xr = bi3[0][i], xz = bi3[1][i], xn = bi3[2][i];
#pragma unroll
            for (int f = 0; f < 4; ++f) {
                xr += xs[f] * wir[0][i][f];
                xz += xs[f] * wir[1][i][f];
                xn += xs[f] * wir[2][i][f];
            }
            const float r = sigmoidf_(xr + ghr[i]);
            const float z = sigmoidf_(xz + ghz[i]);
            const float n = tanhf_(xn + r * ghn[i]);
            hreg[i] = (1.0f - z) * n + z * hreg[i];
        }
        ushort4 hb;
        hb.x = f2bf(hreg[0]); hb.y = f2bf(hreg[1]);
        hb.z = f2bf(hreg[2]); hb.w = f2bf(hreg[3]);
        *(ushort4*)&lds_ah[gb][j0] = hb;
        // y0 layout: [T][B][256] bf16; fwd -> cols 0:128, bwd -> cols 128:256 at orig t
        *(ushort4*)&y0[((size_t)t * Bb + b0 + gb) * 256 + dir * 128 + j0] = hb;
        __syncthreads();
    }
}

// ---------------------------------------------------------------------------
// Layer 1 scan: Gx (K=256, A-frags straight from global y0) + Gh (K=128).
// Writes only final hiddens: finals[b][dir*128 + j].
// ---------------------------------------------------------------------------
__global__ __launch_bounds__(THREADS, 2) void gru_l1(
    const unsigned short* __restrict__ y0,
    const float* __restrict__ wih_f, const float* __restrict__ whh_f,
    const float* __restrict__ bih_f, const float* __restrict__ bhh_f,
    const float* __restrict__ wih_b, const float* __restrict__ whh_b,
    const float* __restrict__ bih_b, const float* __restrict__ bhh_b,
    float* __restrict__ finals)
{
    const int tid  = threadIdx.x;
    const int wave = tid >> 6;
    const int lane = tid & 63;
    const int lcol = lane & 15;
    const int quad = lane >> 4;
    const int dir   = blockIdx.x >> 5;
    const int chunk = blockIdx.x & 31;
    const int b0 = chunk * BC;

    const float* wih = dir ? wih_b : wih_f;
    const float* whh = dir ? whh_b : whh_f;
    const float* bih = dir ? bih_b : bih_f;
    const float* bhh = dir ? bhh_b : bhh_f;

    __shared__ __align__(16) unsigned short lds_ah[BC][136];
    __shared__ __align__(16) float lds_gh[BC][396];
    __shared__ __align__(16) float lds_gx[BC][396];

    // --- preload fragments: whh (K=128) and wih (K=256)
    s16x8 bh[3][4];
    s16x8 bx[3][8];
    float bias_h[3], bias_x[3];
#pragma unroll
    for (int p = 0; p < 3; ++p) {
        const int nrow = (3 * wave + p) * 16 + lcol;
        bias_h[p] = bhh[nrow];
        bias_x[p] = bih[nrow];
#pragma unroll
        for (int kk = 0; kk < 4; ++kk) {
            const float* src = &whh[nrow * Hh + kk * 32 + quad * 8];
            s16x8 f;
#pragma unroll
            for (int j = 0; j < 8; ++j) f[j] = (short)f2bf(src[j]);
            bh[p][kk] = f;
        }
#pragma unroll
        for (int kk = 0; kk < 8; ++kk) {
            const float* src = &wih[nrow * 256 + kk * 32 + quad * 8];
            s16x8 f;
#pragma unroll
            for (int j = 0; j < 8; ++j) f[j] = (short)f2bf(src[j]);
            bx[p][kk] = f;
        }
    }

    const int gb = tid >> 5;
    const int j0 = (tid & 31) * 4;
    float hreg[4] = {0.f, 0.f, 0.f, 0.f};

    for (int idx = tid; idx < BC * 136; idx += THREADS)
        ((unsigned short*)lds_ah)[idx] = 0;
    __syncthreads();

    for (int s = 0; s < Tt; ++s) {
        const int t = dir ? (Tt - 1 - s) : s;
        const unsigned short* ybase = y0 + ((size_t)t * Bb + b0) * 256;

        f32x4 accx[3], acch[3];
#pragma unroll
        for (int p = 0; p < 3; ++p) {
            accx[p] = {bias_x[p], bias_x[p], bias_x[p], bias_x[p]};
            acch[p] = {bias_h[p], bias_h[p], bias_h[p], bias_h[p]};
        }
        // Gx = y0[t] @ wih^T + bih  (A direct from global; 8KB slice is L1-hot)
#pragma unroll
        for (int kk = 0; kk < 8; ++kk) {
            const s16x8 a = *(const s16x8*)&ybase[(size_t)lcol * 256 + kk * 32 + quad * 8];
#pragma unroll
            for (int p = 0; p < 3; ++p)
                accx[p] = __builtin_amdgcn_mfma_f32_16x16x32_bf16(a, bx[p][kk], accx[p], 0, 0, 0);
        }
        // Gh = h @ whh^T + bhh
#pragma unroll
        for (int kk = 0; kk < 4; ++kk) {
            const s16x8 a = *(const s16x8*)&lds_ah[lcol][kk * 32 + quad * 8];
#pragma unroll
            for (int p = 0; p < 3; ++p)
                acch[p] = __builtin_amdgcn_mfma_f32_16x16x32_bf16(a, bh[p][kk], acch[p], 0, 0, 0);
        }
#pragma unroll
        for (int p = 0; p < 3; ++p) {
            const int ncol = (3 * wave + p) * 16 + lcol;
#pragma unroll
            for (int i = 0; i < 4; ++i) {
                lds_gx[quad * 4 + i][ncol] = accx[p][i];
                lds_gh[quad * 4 + i][ncol] = acch[p][i];
            }
        }
        __syncthreads();

        float gxr[4]; *(float4*)gxr = *(const float4*)&lds_gx[gb][j0];
        float gxz[4]; *(float4*)gxz = *(const float4*)&lds_gx[gb][j0 + 128];
        float gxn[4]; *(float4*)gxn = *(const float4*)&lds_gx[gb][j0 + 256];
        float ghr[4]; *(float4*)ghr = *(const float4*)&lds_gh[gb][j0];
        float ghz[4]; *(float4*)ghz = *(const float4*)&lds_gh[gb][j0 + 128];
        float ghn[4]; *(float4*)ghn = *(const float4*)&lds_gh[gb][j0 + 256];
#pragma unroll
        for (int i = 0; i < 4; ++i) {
            const float r = sigmoidf_(gxr[i] + ghr[i]);
            const float z = sigmoidf_(gxz[i] + ghz[i]);
            const float n = tanhf_(gxn[i] + r * ghn[i]);
            hreg[i] = (1.0f - z) * n + z * hreg[i];
        }
        ushort4 hb;
        hb.x = f2bf(hreg[0]); hb.y = f2bf(hreg[1]);
        hb.z = f2bf(hreg[2]); hb.w = f2bf(hreg[3]);
        *(ushort4*)&lds_ah[gb][j0] = hb;
        if (s == Tt - 1) {
            float4 hv; hv.x = hreg[0]; hv.y = hreg[1]; hv.z = hreg[2]; hv.w = hreg[3];
            *(float4*)&finals[(size_t)(b0 + gb) * 256 + dir * 128 + j0] = hv;
        }
        __syncthreads();
    }
}

// ---------------------------------------------------------------------------
// FC head: out = relu(finals @ fc1^T + b1) @ fc2^T + b2   [512,256]->[512,2]
// ---------------------------------------------------------------------------
__global__ __launch_bounds__(128) void fc_head(
    const float* __restrict__ finals,
    const float* __restrict__ fc1w, const float* __restrict__ fc1b,
    const float* __restrict__ fc2w, const float* __restrict__ fc2b,
    float* __restrict__ out)
{
    __shared__ float s_in[256];
    __shared__ float s_h1[128];
    const int b = blockIdx.x, tid = threadIdx.x;
    s_in[tid]       = finals[(size_t)b * 256 + tid];
    s_in[tid + 128] = finals[(size_t)b * 256 + 128 + tid];
    __syncthreads();
    float acc = fc1b[tid];
    const float* wrow = &fc1w[tid * 256];
#pragma unroll 8
    for (int i = 0; i < 256; ++i) acc += s_in[i] * wrow[i];
    s_h1[tid] = fmaxf(acc, 0.0f);
    __syncthreads();
    if (tid < 2) {
        float a = fc2b[tid];
        const float* w2 = &fc2w[tid * 128];
#pragma unroll 8
        for (int i = 0; i < 128; ++i) a += s_h1[i] * w2[i];
        out[b * 2 + tid] = a;
    }
}

extern "C" void kernel_launch(void* const* d_in, const int* in_sizes, int n_in,
                              void* d_out, int out_size, void* d_ws, size_t ws_size,
                              hipStream_t stream) {
    const float* x      = (const float*)d_in[0];
    const float* wih0f  = (const float*)d_in[1];
    const float* whh0f  = (const float*)d_in[2];
    const float* bih0f  = (const float*)d_in[3];
    const float* bhh0f  = (const float*)d_in[4];
    const float* wih0b  = (const float*)d_in[5];
    const float* whh0b  = (const float*)d_in[6];
    const float* bih0b  = (const float*)d_in[7];
    const float* bhh0b  = (const float*)d_in[8];
    const float* wih1f  = (const float*)d_in[9];
    const float* whh1f  = (const float*)d_in[10];
    const float* bih1f  = (const float*)d_in[11];
    const float* bhh1f  = (const float*)d_in[12];
    const float* wih1b  = (const float*)d_in[13];
    const float* whh1b  = (const float*)d_in[14];
    const float* bih1b  = (const float*)d_in[15];
    const float* bhh1b  = (const float*)d_in[16];
    const float* fc1w   = (const float*)d_in[17];
    const float* fc1b   = (const float*)d_in[18];
    const float* fc2w   = (const float*)d_in[19];
    const float* fc2b   = (const float*)d_in[20];

    unsigned short* y0 = (unsigned short*)d_ws;                       // 128 MB bf16
    float* finals = (float*)((char*)d_ws + (size_t)Tt * Bb * 256 * 2); // 512 KB fp32
    float* out = (float*)d_out;

    gru_l0<<<dim3(64), dim3(THREADS), 0, stream>>>(
        x, wih0f, whh0f, bih0f, bhh0f, wih0b, whh0b, bih0b, bhh0b, y0);
    gru_l1<<<dim3(64), dim3(THREADS), 0, stream>>>(
        y0, wih1f, whh1f, bih1f, bhh1f, wih1b, whh1b, bih1b, bhh1b, finals);
    fc_head<<<dim3(Bb), dim3(128), 0, stream>>>(finals, fc1w, fc1b, fc2w, fc2b, out);
}

// Round 2
// 2153.592 us; speedup vs baseline: 1.1423x; 1.1423x over previous
//
#include <hip/hip_runtime.h>
#include <stdint.h>

// GRUClassifier: 2-layer bidirectional GRU (H=128, T=512, B=512) + FC head.
// Latency-optimized scan: one barrier/step, gate math in registers (wave owns
// cols [16w,16w+16) of all 3 gates), h ping-pong in LDS, Gx pipelined one step
// ahead, y0 register-prefetched 2 steps ahead across raw lgkmcnt-only barriers.

#define Tt 512
#define Bb 512
#define THREADS 512

using s16x8 = __attribute__((ext_vector_type(8))) short;  // 8 bf16 (4 VGPRs)
using f32x4 = __attribute__((ext_vector_type(4))) float;

#define MF(a, b, c) __builtin_amdgcn_mfma_f32_16x16x32_bf16((a), (b), (c), 0, 0, 0)

__device__ __forceinline__ unsigned short f2bf(float f) {
    union { float f; unsigned int u; } v; v.f = f;
    unsigned int u = v.u;
    u += 0x7fffu + ((u >> 16) & 1u);   // RNE
    return (unsigned short)(u >> 16);
}

__device__ __forceinline__ float fsig(float x) {
    return __builtin_amdgcn_rcpf(1.0f + __expf(-x));
}
__device__ __forceinline__ float ftanh(float x) {
    return 2.0f * __builtin_amdgcn_rcpf(1.0f + __expf(-2.0f * x)) - 1.0f;
}

// Raw workgroup barrier that does NOT drain vmcnt: in-flight global prefetch
// loads (register destinations) survive it. LDS writes are drained (lgkmcnt 0).
#define WG_BARRIER() asm volatile("s_waitcnt lgkmcnt(0)\n\ts_barrier" ::: "memory")

// ---------------------------------------------------------------------------
// Layer 1 scan. grid = 64 (dir*32 + chunk), block = 512 (8 waves).
// Wave w owns gate-cols [16w,16w+16) for r,z,n (W-tiles w, w+8, w+16).
// ---------------------------------------------------------------------------
__global__ __launch_bounds__(THREADS, 2) void gru_l1(
    const unsigned short* __restrict__ y0,
    const float* __restrict__ wih_f, const float* __restrict__ whh_f,
    const float* __restrict__ bih_f, const float* __restrict__ bhh_f,
    const float* __restrict__ wih_b, const float* __restrict__ whh_b,
    const float* __restrict__ bih_b, const float* __restrict__ bhh_b,
    float* __restrict__ finals)
{
    const int tid  = threadIdx.x;
    const int wave = tid >> 6;
    const int lane = tid & 63;
    const int lcol = lane & 15;
    const int quad = lane >> 4;
    const int dir   = blockIdx.x >> 5;
    const int b0    = (blockIdx.x & 31) * 16;
    const int c     = 16 * wave + lcol;           // this lane's gate column

    const float* wih = dir ? wih_b : wih_f;
    const float* whh = dir ? whh_b : whh_f;
    const float* bih = dir ? bih_b : bih_f;
    const float* bhh = dir ? bhh_b : bhh_f;

    __shared__ __align__(16) unsigned short lds_h[2][16][136]; // h bf16 ping-pong

    // --- biases (r,z summed; n split x/h) ---
    const float br  = bih[c]       + bhh[c];
    const float bz  = bih[128 + c] + bhh[128 + c];
    const float bnx = bih[256 + c];
    const float bnh = bhh[256 + c];

    // --- preload B-fragments: gate p -> W row 128p + c ---
    s16x8 bh[3][4];   // whh, K=128
    s16x8 bx[3][8];   // wih, K=256
#pragma unroll
    for (int p = 0; p < 3; ++p) {
        const int nrow = p * 128 + c;
#pragma unroll
        for (int kk = 0; kk < 4; ++kk) {
            const float* src = &whh[(size_t)nrow * 128 + kk * 32 + quad * 8];
            s16x8 f;
#pragma unroll
            for (int j = 0; j < 8; ++j) f[j] = (short)f2bf(src[j]);
            bh[p][kk] = f;
        }
#pragma unroll
        for (int kk = 0; kk < 8; ++kk) {
            const float* src = &wih[(size_t)nrow * 256 + kk * 32 + quad * 8];
            s16x8 f;
#pragma unroll
            for (int j = 0; j < 8; ++j) f[j] = (short)f2bf(src[j]);
            bx[p][kk] = f;
        }
    }

    // --- y0 A-fragment prefetch (every wave loads the full 16x256 tile;
    //     addresses identical across waves -> L1/MSHR-merged) ---
    auto loadP = [&](s16x8 (&P)[8], int t) {
        const unsigned short* pb = y0 + ((size_t)t * Bb + b0 + lcol) * 256 + quad * 8;
#pragma unroll
        for (int kk = 0; kk < 8; ++kk) P[kk] = *(const s16x8*)(pb + kk * 32);
    };
    s16x8 P0[8], P1[8];
    loadP(P0, dir ? 511 : 0);
    loadP(P1, dir ? 510 : 1);

    // --- Gx prologue for s=0 (x-part of r,z,n chains) ---
    f32x4 accr = {br, br, br, br};
    f32x4 accz = {bz, bz, bz, bz};
    f32x4 accnx = {bnx, bnx, bnx, bnx};
#pragma unroll
    for (int kk = 0; kk < 8; ++kk) {
        accr  = MF(P0[kk], bx[0][kk], accr);
        accz  = MF(P0[kk], bx[1][kk], accz);
        accnx = MF(P0[kk], bx[2][kk], accnx);
    }
    loadP(P0, dir ? 509 : 2);   // reuse buffer for s=2

    float hreg[4] = {0.f, 0.f, 0.f, 0.f};
    for (int idx = tid; idx < 2 * 16 * 136; idx += THREADS)
        ((unsigned short*)lds_h)[idx] = 0;
    __syncthreads();

#define L1_STEP(S, PAR, PN)                                                    \
    do {                                                                       \
        const s16x8 a0 = *(const s16x8*)&lds_h[PAR][lcol][0  + quad * 8];      \
        const s16x8 a1 = *(const s16x8*)&lds_h[PAR][lcol][32 + quad * 8];      \
        const s16x8 a2 = *(const s16x8*)&lds_h[PAR][lcol][64 + quad * 8];      \
        const s16x8 a3 = *(const s16x8*)&lds_h[PAR][lcol][96 + quad * 8];      \
        f32x4 acchn = {bnh, bnh, bnh, bnh};                                    \
        accr = MF(a0, bh[0][0], accr); accz = MF(a0, bh[1][0], accz);          \
        acchn = MF(a0, bh[2][0], acchn);                                       \
        accr = MF(a1, bh[0][1], accr); accz = MF(a1, bh[1][1], accz);          \
        acchn = MF(a1, bh[2][1], acchn);                                       \
        accr = MF(a2, bh[0][2], accr); accz = MF(a2, bh[1][2], accz);          \
        acchn = MF(a2, bh[2][2], acchn);                                       \
        accr = MF(a3, bh[0][3], accr); accz = MF(a3, bh[1][3], accz);          \
        acchn = MF(a3, bh[2][3], acchn);                                       \
        _Pragma("unroll")                                                      \
        for (int i = 0; i < 4; ++i) {                                          \
            const float r = fsig(accr[i]);                                     \
            const float z = fsig(accz[i]);                                     \
            const float n = ftanh(accnx[i] + r * acchn[i]);                    \
            hreg[i] = (1.0f - z) * n + z * hreg[i];                            \
            lds_h[PAR ^ 1][4 * quad + i][c] = f2bf(hreg[i]);                   \
        }                                                                      \
        if ((S) < 511) {                                                       \
            accr = {br, br, br, br}; accz = {bz, bz, bz, bz};                  \
            accnx = {bnx, bnx, bnx, bnx};                                      \
            _Pragma("unroll")                                                  \
            for (int kk = 0; kk < 8; ++kk) {                                   \
                accr  = MF(PN[kk], bx[0][kk], accr);                           \
                accz  = MF(PN[kk], bx[1][kk], accz);                           \
                accnx = MF(PN[kk], bx[2][kk], accnx);                          \
            }                                                                  \
            int sp = (S) + 3; if (sp > 511) sp = 511;                          \
            loadP(PN, dir ? (511 - sp) : sp);                                  \
        } else {                                                               \
            _Pragma("unroll")                                                  \
            for (int i = 0; i < 4; ++i)                                        \
                finals[(size_t)(b0 + 4 * quad + i) * 256 + dir * 128 + c] =    \
                    hreg[i];                                                   \
        }                                                                      \
        WG_BARRIER();                                                          \
    } while (0)

    for (int s = 0; s < Tt; s += 2) {
        L1_STEP(s,     0, P1);
        L1_STEP(s + 1, 1, P0);
    }
#undef L1_STEP
}

// ---------------------------------------------------------------------------
// Layer 0 scan: input dim 4 (pipelined scalar x-projection), Gh via MFMA.
// ---------------------------------------------------------------------------
__global__ __launch_bounds__(THREADS, 2) void gru_l0(
    const float* __restrict__ x,
    const float* __restrict__ wih_f, const float* __restrict__ whh_f,
    const float* __restrict__ bih_f, const float* __restrict__ bhh_f,
    const float* __restrict__ wih_b, const float* __restrict__ whh_b,
    const float* __restrict__ bih_b, const float* __restrict__ bhh_b,
    unsigned short* __restrict__ y0)
{
    const int tid  = threadIdx.x;
    const int wave = tid >> 6;
    const int lane = tid & 63;
    const int lcol = lane & 15;
    const int quad = lane >> 4;
    const int dir   = blockIdx.x >> 5;
    const int b0    = (blockIdx.x & 31) * 16;
    const int c     = 16 * wave + lcol;

    const float* wih = dir ? wih_b : wih_f;
    const float* whh = dir ? whh_b : whh_f;
    const float* bih = dir ? bih_b : bih_f;
    const float* bhh = dir ? bhh_b : bhh_f;

    __shared__ __align__(16) unsigned short lds_h[2][16][136];

    const float brs  = bih[c]       + bhh[c];
    const float bzs  = bih[128 + c] + bhh[128 + c];
    const float bnxs = bih[256 + c];
    const float bnh  = bhh[256 + c];

    // input weights for this lane's column (din=4)
    float wr[4], wz[4], wn[4];
#pragma unroll
    for (int f = 0; f < 4; ++f) {
        wr[f] = wih[(c)       * 4 + f];
        wz[f] = wih[(128 + c) * 4 + f];
        wn[f] = wih[(256 + c) * 4 + f];
    }

    s16x8 bh[3][4];
#pragma unroll
    for (int p = 0; p < 3; ++p) {
        const int nrow = p * 128 + c;
#pragma unroll
        for (int kk = 0; kk < 4; ++kk) {
            const float* src = &whh[(size_t)nrow * 128 + kk * 32 + quad * 8];
            s16x8 f;
#pragma unroll
            for (int j = 0; j < 8; ++j) f[j] = (short)f2bf(src[j]);
            bh[p][kk] = f;
        }
    }

    // x prefetch: lane needs rows b0+4*quad+i (i=0..3), x[row][t][0..3]
    auto loadX = [&](float4 (&X)[4], int t) {
#pragma unroll
        for (int i = 0; i < 4; ++i)
            X[i] = *(const float4*)&x[((size_t)(b0 + 4 * quad + i) * Tt + t) * 4];
    };
    float4 X0[4], X1[4];
    loadX(X0, dir ? 511 : 0);
    loadX(X1, dir ? 510 : 1);

    // x-projection (+ biases) for s=0
    float xpr[4], xpz[4], xpn[4];
#pragma unroll
    for (int i = 0; i < 4; ++i) {
        xpr[i] = brs  + X0[i].x * wr[0] + X0[i].y * wr[1] + X0[i].z * wr[2] + X0[i].w * wr[3];
        xpz[i] = bzs  + X0[i].x * wz[0] + X0[i].y * wz[1] + X0[i].z * wz[2] + X0[i].w * wz[3];
        xpn[i] = bnxs + X0[i].x * wn[0] + X0[i].y * wn[1] + X0[i].z * wn[2] + X0[i].w * wn[3];
    }
    loadX(X0, dir ? 509 : 2);

    float hreg[4] = {0.f, 0.f, 0.f, 0.f};
    for (int idx = tid; idx < 2 * 16 * 136; idx += THREADS)
        ((unsigned short*)lds_h)[idx] = 0;
    __syncthreads();

#define L0_STEP(S, PAR, XN)                                                    \
    do {                                                                       \
        const int t = dir ? (511 - (S)) : (S);                                 \
        const s16x8 a0 = *(const s16x8*)&lds_h[PAR][lcol][0  + quad * 8];      \
        const s16x8 a1 = *(const s16x8*)&lds_h[PAR][lcol][32 + quad * 8];      \
        const s16x8 a2 = *(const s16x8*)&lds_h[PAR][lcol][64 + quad * 8];      \
        const s16x8 a3 = *(const s16x8*)&lds_h[PAR][lcol][96 + quad * 8];      \
        f32x4 accr  = {xpr[0], xpr[1], xpr[2], xpr[3]};                        \
        f32x4 accz  = {xpz[0], xpz[1], xpz[2], xpz[3]};                        \
        f32x4 acchn = {bnh, bnh, bnh, bnh};                                    \
        accr = MF(a0, bh[0][0], accr); accz = MF(a0, bh[1][0], accz);          \
        acchn = MF(a0, bh[2][0], acchn);                                       \
        accr = MF(a1, bh[0][1], accr); accz = MF(a1, bh[1][1], accz);          \
        acchn = MF(a1, bh[2][1], acchn);                                       \
        accr = MF(a2, bh[0][2], accr); accz = MF(a2, bh[1][2], accz);          \
        acchn = MF(a2, bh[2][2], acchn);                                       \
        accr = MF(a3, bh[0][3], accr); accz = MF(a3, bh[1][3], accz);          \
        acchn = MF(a3, bh[2][3], acchn);                                       \
        _Pragma("unroll")                                                      \
        for (int i = 0; i < 4; ++i) {                                          \
            const float r = fsig(accr[i]);                                     \
            const float z = fsig(accz[i]);                                     \
            const float n = ftanh(xpn[i] + r * acchn[i]);                      \
            hreg[i] = (1.0f - z) * n + z * hreg[i];                            \
            const unsigned short hb = f2bf(hreg[i]);                           \
            lds_h[PAR ^ 1][4 * quad + i][c] = hb;                              \
            y0[((size_t)t * Bb + b0 + 4 * quad + i) * 256 + dir * 128 + c] = hb; \
        }                                                                      \
        if ((S) < 511) {                                                       \
            _Pragma("unroll")                                                  \
            for (int i = 0; i < 4; ++i) {                                      \
                xpr[i] = brs  + XN[i].x * wr[0] + XN[i].y * wr[1]              \
                              + XN[i].z * wr[2] + XN[i].w * wr[3];             \
                xpz[i] = bzs  + XN[i].x * wz[0] + XN[i].y * wz[1]              \
                              + XN[i].z * wz[2] + XN[i].w * wz[3];             \
                xpn[i] = bnxs + XN[i].x * wn[0] + XN[i].y * wn[1]              \
                              + XN[i].z * wn[2] + XN[i].w * wn[3];             \
            }                                                                  \
            int sp = (S) + 3; if (sp > 511) sp = 511;                          \
            loadX(XN, dir ? (511 - sp) : sp);                                  \
        }                                                                      \
        WG_BARRIER();                                                          \
    } while (0)

    for (int s = 0; s < Tt; s += 2) {
        L0_STEP(s,     0, X1);
        L0_STEP(s + 1, 1, X0);
    }
#undef L0_STEP
}

// ---------------------------------------------------------------------------
// FC head: out = relu(finals @ fc1^T + b1) @ fc2^T + b2   [512,256]->[512,2]
// ---------------------------------------------------------------------------
__global__ __launch_bounds__(128) void fc_head(
    const float* __restrict__ finals,
    const float* __restrict__ fc1w, const float* __restrict__ fc1b,
    const float* __restrict__ fc2w, const float* __restrict__ fc2b,
    float* __restrict__ out)
{
    __shared__ float s_in[256];
    __shared__ float s_h1[128];
    const int b = blockIdx.x, tid = threadIdx.x;
    s_in[tid]       = finals[(size_t)b * 256 + tid];
    s_in[tid + 128] = finals[(size_t)b * 256 + 128 + tid];
    __syncthreads();
    float acc = fc1b[tid];
    const float* wrow = &fc1w[tid * 256];
#pragma unroll 8
    for (int i = 0; i < 256; ++i) acc += s_in[i] * wrow[i];
    s_h1[tid] = fmaxf(acc, 0.0f);
    __syncthreads();
    if (tid < 2) {
        float a = fc2b[tid];
        const float* w2 = &fc2w[tid * 128];
#pragma unroll 8
        for (int i = 0; i < 128; ++i) a += s_h1[i] * w2[i];
        out[b * 2 + tid] = a;
    }
}

extern "C" void kernel_launch(void* const* d_in, const int* in_sizes, int n_in,
                              void* d_out, int out_size, void* d_ws, size_t ws_size,
                              hipStream_t stream) {
    const float* x      = (const float*)d_in[0];
    const float* wih0f  = (const float*)d_in[1];
    const float* whh0f  = (const float*)d_in[2];
    const float* bih0f  = (const float*)d_in[3];
    const float* bhh0f  = (const float*)d_in[4];
    const float* wih0b  = (const float*)d_in[5];
    const float* whh0b  = (const float*)d_in[6];
    const float* bih0b  = (const float*)d_in[7];
    const float* bhh0b  = (const float*)d_in[8];
    const float* wih1f  = (const float*)d_in[9];
    const float* whh1f  = (const float*)d_in[10];
    const float* bih1f  = (const float*)d_in[11];
    const float* bhh1f  = (const float*)d_in[12];
    const float* wih1b  = (const float*)d_in[13];
    const float* whh1b  = (const float*)d_in[14];
    const float* bih1b  = (const float*)d_in[15];
    const float* bhh1b  = (const float*)d_in[16];
    const float* fc1w   = (const float*)d_in[17];
    const float* fc1b   = (const float*)d_in[18];
    const float* fc2w   = (const float*)d_in[19];
    const float* fc2b   = (const float*)d_in[20];

    unsigned short* y0 = (unsigned short*)d_ws;                         // 128 MB bf16
    float* finals = (float*)((char*)d_ws + (size_t)Tt * Bb * 256 * 2);  // 512 KB fp32
    float* out = (float*)d_out;

    gru_l0<<<dim3(64), dim3(THREADS), 0, stream>>>(
        x, wih0f, whh0f, bih0f, bhh0f, wih0b, whh0b, bih0b, bhh0b, y0);
    gru_l1<<<dim3(64), dim3(THREADS), 0, stream>>>(
        y0, wih1f, whh1f, bih1f, bhh1f, wih1b, whh1b, bih1b, bhh1b, finals);
    fc_head<<<dim3(Bb), dim3(128), 0, stream>>>(finals, fc1w, fc1b, fc2w, fc2b, out);
}

// Round 3
// 2130.446 us; speedup vs baseline: 1.1547x; 1.0109x over previous
//
#include <hip/hip_runtime.h>
#include <stdint.h>

// GRUClassifier: 2-layer bidirectional GRU (H=128, T=512, B=512) + FC head.
// Latency-optimized scan: one barrier/step, gate math in registers (wave owns
// cols [16w,16w+16) of all 3 gates), h ping-pong in LDS, Gx pipelined one step
// ahead, y0 register-prefetched 2 steps ahead across raw lgkmcnt-only barriers.
// launch_bounds(512,1): 1 block/CU, 256 VGPR/wave -> weight fragments stay
// register-resident (R2's (512,2) capped at 128 VGPRs and spilled every step).

#define Tt 512
#define Bb 512
#define THREADS 512

using s16x8 = __attribute__((ext_vector_type(8))) short;  // 8 bf16 (4 VGPRs)
using f32x4 = __attribute__((ext_vector_type(4))) float;

#define MF(a, b, c) __builtin_amdgcn_mfma_f32_16x16x32_bf16((a), (b), (c), 0, 0, 0)

__device__ __forceinline__ unsigned short f2bf(float f) {
    union { float f; unsigned int u; } v; v.f = f;
    unsigned int u = v.u;
    u += 0x7fffu + ((u >> 16) & 1u);   // RNE
    return (unsigned short)(u >> 16);
}

__device__ __forceinline__ float fsig(float x) {
    return __builtin_amdgcn_rcpf(1.0f + __expf(-x));
}
__device__ __forceinline__ float ftanh(float x) {
    return 2.0f * __builtin_amdgcn_rcpf(1.0f + __expf(-2.0f * x)) - 1.0f;
}

// Raw workgroup barrier that does NOT drain vmcnt: in-flight global prefetch
// loads (register destinations) survive it. LDS writes are drained (lgkmcnt 0).
#define WG_BARRIER() asm volatile("s_waitcnt lgkmcnt(0)\n\ts_barrier" ::: "memory")

// ---------------------------------------------------------------------------
// Layer 1 scan. grid = 64 (dir*32 + chunk), block = 512 (8 waves).
// Wave w owns gate-cols [16w,16w+16) for r,z,n (W-tiles w, w+8, w+16).
// ---------------------------------------------------------------------------
__global__ __launch_bounds__(THREADS, 1) void gru_l1(
    const unsigned short* __restrict__ y0,
    const float* __restrict__ wih_f, const float* __restrict__ whh_f,
    const float* __restrict__ bih_f, const float* __restrict__ bhh_f,
    const float* __restrict__ wih_b, const float* __restrict__ whh_b,
    const float* __restrict__ bih_b, const float* __restrict__ bhh_b,
    float* __restrict__ finals)
{
    const int tid  = threadIdx.x;
    const int wave = tid >> 6;
    const int lane = tid & 63;
    const int lcol = lane & 15;
    const int quad = lane >> 4;
    const int dir   = blockIdx.x >> 5;
    const int b0    = (blockIdx.x & 31) * 16;
    const int c     = 16 * wave + lcol;           // this lane's gate column

    const float* wih = dir ? wih_b : wih_f;
    const float* whh = dir ? whh_b : whh_f;
    const float* bih = dir ? bih_b : bih_f;
    const float* bhh = dir ? bhh_b : bhh_f;

    __shared__ __align__(16) unsigned short lds_h[2][16][136]; // h bf16 ping-pong

    // --- biases (r,z summed; n split x/h) ---
    const float br  = bih[c]       + bhh[c];
    const float bz  = bih[128 + c] + bhh[128 + c];
    const float bnx = bih[256 + c];
    const float bnh = bhh[256 + c];

    // --- preload B-fragments: gate p -> W row 128p + c ---
    s16x8 bh[3][4];   // whh, K=128
    s16x8 bx[3][8];   // wih, K=256
#pragma unroll
    for (int p = 0; p < 3; ++p) {
        const int nrow = p * 128 + c;
#pragma unroll
        for (int kk = 0; kk < 4; ++kk) {
            const float* src = &whh[(size_t)nrow * 128 + kk * 32 + quad * 8];
            s16x8 f;
#pragma unroll
            for (int j = 0; j < 8; ++j) f[j] = (short)f2bf(src[j]);
            bh[p][kk] = f;
        }
#pragma unroll
        for (int kk = 0; kk < 8; ++kk) {
            const float* src = &wih[(size_t)nrow * 256 + kk * 32 + quad * 8];
            s16x8 f;
#pragma unroll
            for (int j = 0; j < 8; ++j) f[j] = (short)f2bf(src[j]);
            bx[p][kk] = f;
        }
    }

    // --- y0 A-fragment prefetch (every wave loads the full 16x256 tile;
    //     addresses identical across waves -> L1/MSHR-merged) ---
    auto loadP = [&](s16x8 (&P)[8], int t) {
        const unsigned short* pb = y0 + ((size_t)t * Bb + b0 + lcol) * 256 + quad * 8;
#pragma unroll
        for (int kk = 0; kk < 8; ++kk) P[kk] = *(const s16x8*)(pb + kk * 32);
    };
    s16x8 P0[8], P1[8];
    loadP(P0, dir ? 511 : 0);
    loadP(P1, dir ? 510 : 1);

    // --- Gx prologue for s=0 (x-part of r,z,n chains) ---
    f32x4 accr = {br, br, br, br};
    f32x4 accz = {bz, bz, bz, bz};
    f32x4 accnx = {bnx, bnx, bnx, bnx};
#pragma unroll
    for (int kk = 0; kk < 8; ++kk) {
        accr  = MF(P0[kk], bx[0][kk], accr);
        accz  = MF(P0[kk], bx[1][kk], accz);
        accnx = MF(P0[kk], bx[2][kk], accnx);
    }
    loadP(P0, dir ? 509 : 2);   // reuse buffer for s=2

    float hreg[4] = {0.f, 0.f, 0.f, 0.f};
    for (int idx = tid; idx < 2 * 16 * 136; idx += THREADS)
        ((unsigned short*)lds_h)[idx] = 0;
    __syncthreads();

#define L1_STEP(S, PAR, PN)                                                    \
    do {                                                                       \
        const s16x8 a0 = *(const s16x8*)&lds_h[PAR][lcol][0  + quad * 8];      \
        const s16x8 a1 = *(const s16x8*)&lds_h[PAR][lcol][32 + quad * 8];      \
        const s16x8 a2 = *(const s16x8*)&lds_h[PAR][lcol][64 + quad * 8];      \
        const s16x8 a3 = *(const s16x8*)&lds_h[PAR][lcol][96 + quad * 8];      \
        f32x4 acchn = {bnh, bnh, bnh, bnh};                                    \
        accr = MF(a0, bh[0][0], accr); accz = MF(a0, bh[1][0], accz);          \
        acchn = MF(a0, bh[2][0], acchn);                                       \
        accr = MF(a1, bh[0][1], accr); accz = MF(a1, bh[1][1], accz);          \
        acchn = MF(a1, bh[2][1], acchn);                                       \
        accr = MF(a2, bh[0][2], accr); accz = MF(a2, bh[1][2], accz);          \
        acchn = MF(a2, bh[2][2], acchn);                                       \
        accr = MF(a3, bh[0][3], accr); accz = MF(a3, bh[1][3], accz);          \
        acchn = MF(a3, bh[2][3], acchn);                                       \
        _Pragma("unroll")                                                      \
        for (int i = 0; i < 4; ++i) {                                          \
            const float r = fsig(accr[i]);                                     \
            const float z = fsig(accz[i]);                                     \
            const float n = ftanh(accnx[i] + r * acchn[i]);                    \
            hreg[i] = (1.0f - z) * n + z * hreg[i];                            \
            lds_h[PAR ^ 1][4 * quad + i][c] = f2bf(hreg[i]);                   \
        }                                                                      \
        if ((S) < 511) {                                                       \
            accr = {br, br, br, br}; accz = {bz, bz, bz, bz};                  \
            accnx = {bnx, bnx, bnx, bnx};                                      \
            _Pragma("unroll")                                                  \
            for (int kk = 0; kk < 8; ++kk) {                                   \
                accr  = MF(PN[kk], bx[0][kk], accr);                           \
                accz  = MF(PN[kk], bx[1][kk], accz);                           \
                accnx = MF(PN[kk], bx[2][kk], accnx);                          \
            }                                                                  \
            int sp = (S) + 3; if (sp > 511) sp = 511;                          \
            loadP(PN, dir ? (511 - sp) : sp);                                  \
        } else {                                                               \
            _Pragma("unroll")                                                  \
            for (int i = 0; i < 4; ++i)                                        \
                finals[(size_t)(b0 + 4 * quad + i) * 256 + dir * 128 + c] =    \
                    hreg[i];                                                   \
        }                                                                      \
        WG_BARRIER();                                                          \
    } while (0)

    for (int s = 0; s < Tt; s += 2) {
        L1_STEP(s,     0, P1);
        L1_STEP(s + 1, 1, P0);
    }
#undef L1_STEP
}

// ---------------------------------------------------------------------------
// Layer 0 scan: input dim 4 (pipelined scalar x-projection), Gh via MFMA.
// y0 written coalesced (ushort4/thread) via LDS re-read after the barrier.
// ---------------------------------------------------------------------------
__global__ __launch_bounds__(THREADS, 1) void gru_l0(
    const float* __restrict__ x,
    const float* __restrict__ wih_f, const float* __restrict__ whh_f,
    const float* __restrict__ bih_f, const float* __restrict__ bhh_f,
    const float* __restrict__ wih_b, const float* __restrict__ whh_b,
    const float* __restrict__ bih_b, const float* __restrict__ bhh_b,
    unsigned short* __restrict__ y0)
{
    const int tid  = threadIdx.x;
    const int wave = tid >> 6;
    const int lane = tid & 63;
    const int lcol = lane & 15;
    const int quad = lane >> 4;
    const int dir   = blockIdx.x >> 5;
    const int b0    = (blockIdx.x & 31) * 16;
    const int c     = 16 * wave + lcol;

    const float* wih = dir ? wih_b : wih_f;
    const float* whh = dir ? whh_b : whh_f;
    const float* bih = dir ? bih_b : bih_f;
    const float* bhh = dir ? bhh_b : bhh_f;

    __shared__ __align__(16) unsigned short lds_h[2][16][136];

    const float brs  = bih[c]       + bhh[c];
    const float bzs  = bih[128 + c] + bhh[128 + c];
    const float bnxs = bih[256 + c];
    const float bnh  = bhh[256 + c];

    // input weights for this lane's column (din=4)
    float wr[4], wz[4], wn[4];
#pragma unroll
    for (int f = 0; f < 4; ++f) {
        wr[f] = wih[(c)       * 4 + f];
        wz[f] = wih[(128 + c) * 4 + f];
        wn[f] = wih[(256 + c) * 4 + f];
    }

    s16x8 bh[3][4];
#pragma unroll
    for (int p = 0; p < 3; ++p) {
        const int nrow = p * 128 + c;
#pragma unroll
        for (int kk = 0; kk < 4; ++kk) {
            const float* src = &whh[(size_t)nrow * 128 + kk * 32 + quad * 8];
            s16x8 f;
#pragma unroll
            for (int j = 0; j < 8; ++j) f[j] = (short)f2bf(src[j]);
            bh[p][kk] = f;
        }
    }

    // x prefetch: lane needs rows b0+4*quad+i (i=0..3), x[row][t][0..3]
    auto loadX = [&](float4 (&X)[4], int t) {
#pragma unroll
        for (int i = 0; i < 4; ++i)
            X[i] = *(const float4*)&x[((size_t)(b0 + 4 * quad + i) * Tt + t) * 4];
    };
    float4 X0[4], X1[4];
    loadX(X0, dir ? 511 : 0);
    loadX(X1, dir ? 510 : 1);

    // x-projection (+ biases) for s=0
    float xpr[4], xpz[4], xpn[4];
#pragma unroll
    for (int i = 0; i < 4; ++i) {
        xpr[i] = brs  + X0[i].x * wr[0] + X0[i].y * wr[1] + X0[i].z * wr[2] + X0[i].w * wr[3];
        xpz[i] = bzs  + X0[i].x * wz[0] + X0[i].y * wz[1] + X0[i].z * wz[2] + X0[i].w * wz[3];
        xpn[i] = bnxs + X0[i].x * wn[0] + X0[i].y * wn[1] + X0[i].z * wn[2] + X0[i].w * wn[3];
    }
    loadX(X0, dir ? 509 : 2);

    float hreg[4] = {0.f, 0.f, 0.f, 0.f};
    for (int idx = tid; idx < 2 * 16 * 136; idx += THREADS)
        ((unsigned short*)lds_h)[idx] = 0;
    __syncthreads();

    const int orow = tid >> 5;            // y0 store: row 0..15
    const int oc4  = (tid & 31) * 4;      // col group 0..124

#define L0_STEP(S, PAR, XN)                                                    \
    do {                                                                       \
        const int t = dir ? (511 - (S)) : (S);                                 \
        const s16x8 a0 = *(const s16x8*)&lds_h[PAR][lcol][0  + quad * 8];      \
        const s16x8 a1 = *(const s16x8*)&lds_h[PAR][lcol][32 + quad * 8];      \
        const s16x8 a2 = *(const s16x8*)&lds_h[PAR][lcol][64 + quad * 8];      \
        const s16x8 a3 = *(const s16x8*)&lds_h[PAR][lcol][96 + quad * 8];      \
        f32x4 accr  = {xpr[0], xpr[1], xpr[2], xpr[3]};                        \
        f32x4 accz  = {xpz[0], xpz[1], xpz[2], xpz[3]};                        \
        f32x4 acchn = {bnh, bnh, bnh, bnh};                                    \
        accr = MF(a0, bh[0][0], accr); accz = MF(a0, bh[1][0], accz);          \
        acchn = MF(a0, bh[2][0], acchn);                                       \
        accr = MF(a1, bh[0][1], accr); accz = MF(a1, bh[1][1], accz);          \
        acchn = MF(a1, bh[2][1], acchn);                                       \
        accr = MF(a2, bh[0][2], accr); accz = MF(a2, bh[1][2], accz);          \
        acchn = MF(a2, bh[2][2], acchn);                                       \
        accr = MF(a3, bh[0][3], accr); accz = MF(a3, bh[1][3], accz);          \
        acchn = MF(a3, bh[2][3], acchn);                                       \
        _Pragma("unroll")                                                      \
        for (int i = 0; i < 4; ++i) {                                          \
            const float r = fsig(accr[i]);                                     \
            const float z = fsig(accz[i]);                                     \
            const float n = ftanh(xpn[i] + r * acchn[i]);                      \
            hreg[i] = (1.0f - z) * n + z * hreg[i];                            \
            lds_h[PAR ^ 1][4 * quad + i][c] = f2bf(hreg[i]);                   \
        }                                                                      \
        if ((S) < 511) {                                                       \
            _Pragma("unroll")                                                  \
            for (int i = 0; i < 4; ++i) {                                      \
                xpr[i] = brs  + XN[i].x * wr[0] + XN[i].y * wr[1]              \
                              + XN[i].z * wr[2] + XN[i].w * wr[3];             \
                xpz[i] = bzs  + XN[i].x * wz[0] + XN[i].y * wz[1]              \
                              + XN[i].z * wz[2] + XN[i].w * wz[3];             \
                xpn[i] = bnxs + XN[i].x * wn[0] + XN[i].y * wn[1]              \
                              + XN[i].z * wn[2] + XN[i].w * wn[3];             \
            }                                                                  \
            int sp = (S) + 3; if (sp > 511) sp = 511;                          \
            loadX(XN, dir ? (511 - sp) : sp);                                  \
        }                                                                      \
        WG_BARRIER();                                                          \
        /* coalesced y0 store from the buffer just completed (reads only) */   \
        {                                                                      \
            const ushort4 hv4 = *(const ushort4*)&lds_h[PAR ^ 1][orow][oc4];   \
            *(ushort4*)&y0[((size_t)t * Bb + b0 + orow) * 256 + dir * 128 +    \
                           oc4] = hv4;                                         \
        }                                                                      \
    } while (0)

    for (int s = 0; s < Tt; s += 2) {
        L0_STEP(s,     0, X1);
        L0_STEP(s + 1, 1, X0);
    }
#undef L0_STEP
}

// ---------------------------------------------------------------------------
// FC head: out = relu(finals @ fc1^T + b1) @ fc2^T + b2   [512,256]->[512,2]
// ---------------------------------------------------------------------------
__global__ __launch_bounds__(128) void fc_head(
    const float* __restrict__ finals,
    const float* __restrict__ fc1w, const float* __restrict__ fc1b,
    const float* __restrict__ fc2w, const float* __restrict__ fc2b,
    float* __restrict__ out)
{
    __shared__ float s_in[256];
    __shared__ float s_h1[128];
    const int b = blockIdx.x, tid = threadIdx.x;
    s_in[tid]       = finals[(size_t)b * 256 + tid];
    s_in[tid + 128] = finals[(size_t)b * 256 + 128 + tid];
    __syncthreads();
    float acc = fc1b[tid];
    const float* wrow = &fc1w[tid * 256];
#pragma unroll 8
    for (int i = 0; i < 256; ++i) acc += s_in[i] * wrow[i];
    s_h1[tid] = fmaxf(acc, 0.0f);
    __syncthreads();
    if (tid < 2) {
        float a = fc2b[tid];
        const float* w2 = &fc2w[tid * 128];
#pragma unroll 8
        for (int i = 0; i < 128; ++i) a += s_h1[i] * w2[i];
        out[b * 2 + tid] = a;
    }
}

extern "C" void kernel_launch(void* const* d_in, const int* in_sizes, int n_in,
                              void* d_out, int out_size, void* d_ws, size_t ws_size,
                              hipStream_t stream) {
    const float* x      = (const float*)d_in[0];
    const float* wih0f  = (const float*)d_in[1];
    const float* whh0f  = (const float*)d_in[2];
    const float* bih0f  = (const float*)d_in[3];
    const float* bhh0f  = (const float*)d_in[4];
    const float* wih0b  = (const float*)d_in[5];
    const float* whh0b  = (const float*)d_in[6];
    const float* bih0b  = (const float*)d_in[7];
    const float* bhh0b  = (const float*)d_in[8];
    const float* wih1f  = (const float*)d_in[9];
    const float* whh1f  = (const float*)d_in[10];
    const float* bih1f  = (const float*)d_in[11];
    const float* bhh1f  = (const float*)d_in[12];
    const float* wih1b  = (const float*)d_in[13];
    const float* whh1b  = (const float*)d_in[14];
    const float* bih1b  = (const float*)d_in[15];
    const float* bhh1b  = (const float*)d_in[16];
    const float* fc1w   = (const float*)d_in[17];
    const float* fc1b   = (const float*)d_in[18];
    const float* fc2w   = (const float*)d_in[19];
    const float* fc2b   = (const float*)d_in[20];

    unsigned short* y0 = (unsigned short*)d_ws;                         // 128 MB bf16
    float* finals = (float*)((char*)d_ws + (size_t)Tt * Bb * 256 * 2);  // 512 KB fp32
    float* out = (float*)d_out;

    gru_l0<<<dim3(64), dim3(THREADS), 0, stream>>>(
        x, wih0f, whh0f, bih0f, bhh0f, wih0b, whh0b, bih0b, bhh0b, y0);
    gru_l1<<<dim3(64), dim3(THREADS), 0, stream>>>(
        y0, wih1f, whh1f, bih1f, bhh1f, wih1b, whh1b, bih1b, bhh1b, finals);
    fc_head<<<dim3(Bb), dim3(128), 0, stream>>>(finals, fc1w, fc1b, fc2w, fc2b, out);
}